// Round 3
// baseline (787.623 us; speedup 1.0000x reference)
//
#include <hip/hip_runtime.h>
#include <math.h>

#define Bb 8
#define Tt 1000
#define TPAD 1024
#define NHh 8
#define Dd 64

typedef short bf16x8 __attribute__((ext_vector_type(8)));
typedef float f32x4 __attribute__((ext_vector_type(4)));

#define QOFF (-0.3f)
#define QSTEP (0.6f / 256.0f)
#define QINV (256.0f / 0.6f)
// p = exp2(CQ * sad)  where score = -(1/8)*STEP*sad
#define CQ (-0.125f * 1.44269504088896341f * QSTEP)

__device__ __forceinline__ unsigned sad_u8(unsigned a, unsigned b, unsigned c) {
#if __has_builtin(__builtin_amdgcn_sad_u8)
    return __builtin_amdgcn_sad_u8(a, b, c);
#else
    unsigned d;
    asm("v_sad_u8 %0, %1, %2, %3" : "=v"(d) : "v"(a), "v"(b), "v"(c));
    return d;
#endif
}

__device__ __forceinline__ unsigned quant8(float v) {
    float t = (v - QOFF) * QINV + 0.5f;
    t = fminf(fmaxf(t, 0.0f), 255.0f);
    return (unsigned)(int)t;
}

__device__ __forceinline__ unsigned cvt_pk_bf16(float lo, float hi) {
    unsigned r;
    asm("v_cvt_pk_bf16_f32 %0, %1, %2" : "=v"(r) : "v"(lo), "v"(hi));
    return r;
}

__device__ __forceinline__ bf16x8 mkbf(unsigned u0, unsigned u1, unsigned u2, unsigned u3) {
    union { unsigned u[4]; bf16x8 v; } x;
    x.u[0] = u0; x.u[1] = u1; x.u[2] = u2; x.u[3] = u3;
    return x.v;
}

__device__ __forceinline__ bf16x8 bfc(uint4 q) {
    union { uint4 q; bf16x8 v; } x; x.q = q; return x.v;
}

// ---------------- Kernel A: prep ----------------
// cb<8: q GEMM -> qq8 (u8, packed 4/dword, [bh][1024][16]dw)  +  k quantize -> kq8 (same layout)
// cb>=8: v GEMM -> vfrag bf16 B-fragment layout [bh][st][kk*4+n][lane] of 16B
__global__ __launch_bounds__(256) void prep_kernel(
    const float* __restrict__ x, const float* __restrict__ wq,
    const float* __restrict__ wv, const float* __restrict__ wk,
    unsigned* __restrict__ qq8, unsigned* __restrict__ kq8,
    uint4* __restrict__ vfrag)
{
    __shared__ float xs[64][68];
    __shared__ float ws[64][65];
    __shared__ float vS[64][68];
    const int tid = threadIdx.x;
    const int st = blockIdx.x;      // 0..15 token tile within (b)
    const int cb = blockIdx.y;      // 0..15
    const int b  = blockIdx.z;
    const bool isQ = (cb < 8);
    const int h = isQ ? cb : (cb - 8);
    const float* W = isQ ? wq : wv;
    const int cBase = h * 64;
    const int bh = b * NHh + h;

#pragma unroll
    for (int i = 0; i < 4; ++i) {
        int f4 = tid + i * 256;
        int r = f4 >> 4, c4 = (f4 & 15) << 2;
        int row = st * 64 + r; if (row >= Tt) row = Tt - 1;
        *(float4*)&xs[r][c4] = *(const float4*)&x[((size_t)b * Tt + row) * 64 + c4];
    }
#pragma unroll
    for (int i = 0; i < 16; ++i) {
        int idx = tid + i * 256;
        int c = idx >> 6, k = idx & 63;
        ws[c][k] = W[(cBase + c) * 65 + k];
    }
    __syncthreads();

    const int rg = tid >> 4, cg = tid & 15;
    const int r0 = rg * 4, c0 = cg * 4;
    float acc[4][4];
#pragma unroll
    for (int j = 0; j < 4; ++j) {
        float bias = W[(cBase + c0 + j) * 65 + 64];
#pragma unroll
        for (int i = 0; i < 4; ++i) acc[i][j] = bias;
    }
    for (int k0 = 0; k0 < 64; k0 += 4) {
        float4 a[4];
#pragma unroll
        for (int i = 0; i < 4; ++i) a[i] = *(const float4*)&xs[r0 + i][k0];
#pragma unroll
        for (int j = 0; j < 4; ++j) {
            float b0 = ws[c0 + j][k0 + 0];
            float b1 = ws[c0 + j][k0 + 1];
            float b2 = ws[c0 + j][k0 + 2];
            float b3 = ws[c0 + j][k0 + 3];
#pragma unroll
            for (int i = 0; i < 4; ++i)
                acc[i][j] += a[i].x * b0 + a[i].y * b1 + a[i].z * b2 + a[i].w * b3;
        }
    }

    if (isQ) {
        // q -> qq8
#pragma unroll
        for (int i = 0; i < 4; ++i) {
            int t = st * 64 + r0 + i;
            unsigned d = 0u;
            if (t < Tt)
                d = quant8(acc[i][0]) | (quant8(acc[i][1]) << 8) |
                    (quant8(acc[i][2]) << 16) | (quant8(acc[i][3]) << 24);
            qq8[((size_t)bh * TPAD + t) * 16 + cg] = d;
        }
        // k = x*wk[h] -> kq8 : thread handles row tid>>2, 16 w's at (tid&3)*16
        {
            const int r = tid >> 2, c4 = tid & 3;
            const int t = st * 64 + r;
            unsigned kd[4];
            if (t < Tt) {
#pragma unroll
                for (int dw = 0; dw < 4; ++dw) {
                    int w = c4 * 16 + dw * 4;
                    float4 wkv = *(const float4*)&wk[h * 64 + w];
                    kd[dw] = quant8(xs[r][w + 0] * wkv.x) |
                             (quant8(xs[r][w + 1] * wkv.y) << 8) |
                             (quant8(xs[r][w + 2] * wkv.z) << 16) |
                             (quant8(xs[r][w + 3] * wkv.w) << 24);
                }
            } else {
                kd[0] = kd[1] = kd[2] = kd[3] = 0u;
            }
            *(uint4*)&kq8[((size_t)bh * TPAD + t) * 16 + c4 * 4] =
                make_uint4(kd[0], kd[1], kd[2], kd[3]);
        }
    } else {
        // v -> vS -> bf16 fragment layout
#pragma unroll
        for (int i = 0; i < 4; ++i) {
            float4 o; o.x = acc[i][0]; o.y = acc[i][1]; o.z = acc[i][2]; o.w = acc[i][3];
            *(float4*)&vS[r0 + i][c0] = o;
        }
        __syncthreads();
#pragma unroll
        for (int e2 = 0; e2 < 2; ++e2) {
            int ent = tid + e2 * 256;       // 0..511 = kk*256 + n*64 + lane
            int kk = ent >> 8, rem = ent & 255, n = rem >> 6, lane = rem & 63;
            int ts = kk * 32 + ((lane >> 4) << 3);
            int w  = n * 16 + (lane & 15);
            unsigned o[4];
#pragma unroll
            for (int pr = 0; pr < 4; ++pr) {
                int t0 = st * 64 + ts + pr * 2;
                float lo = (t0 < Tt)     ? vS[ts + pr * 2][w]     : 0.0f;
                float hi = (t0 + 1 < Tt) ? vS[ts + pr * 2 + 1][w] : 0.0f;
                o[pr] = cvt_pk_bf16(lo, hi);
            }
            vfrag[(((size_t)bh * 16 + st) * 8 + (kk * 4 + n)) * 64 + lane] =
                make_uint4(o[0], o[1], o[2], o[3]);
        }
    }
}

// ---------------- Kernel B: attention, 4 waves/block, LDS cross-wave reduce ----------------
// Wave w handles source tiles {w, w+4, w+8, w+12}; lane l: P rows tq = qt*16 + (l&15);
// ts = tile*64 + kk*32 + (l>>4)*8 + e (A-frag layout). Numerators+denoms reduced via LDS.
__global__ __launch_bounds__(256, 8) void attn_kernel(
    const unsigned* __restrict__ qq8, const unsigned* __restrict__ kq8,
    const uint4* __restrict__ vfrag, float* __restrict__ part)
{
    __shared__ float red[16][4][64];   // [v=n*4+j][wave][lane] — lane-major: conflict-free
    __shared__ float dred[4][16];      // [wave][m]

    const int tid = threadIdx.x;
    const int wv_ = tid >> 6;          // wave 0..3
    const int l   = tid & 63;
    const int qt  = blockIdx.x;        // 0..62
    const int h   = blockIdx.y, b = blockIdx.z;
    const int bh  = b * NHh + h;
    const int g   = l >> 4;            // 0..3
    const int m   = l & 15;

    // q row (16 dwords = 64 u8)
    unsigned qv[16];
    {
        const uint4* qp = (const uint4*)(qq8 + ((size_t)bh * TPAD + qt * 16 + m) * 16);
        *(uint4*)&qv[0]  = qp[0];
        *(uint4*)&qv[4]  = qp[1];
        *(uint4*)&qv[8]  = qp[2];
        *(uint4*)&qv[12] = qp[3];
    }

    // k pointer: start at wave's first tile, group g's first row (uint4 units; row = 4 uint4)
    const uint4* kp = (const uint4*)(kq8 + (size_t)bh * TPAD * 16) + (size_t)wv_ * 256 + g * 8 * 4;
    // v fragments: entry lane l of wave's first tile; entries stride 64, tiles stride 512
    const uint4* vp = vfrag + (size_t)bh * 16 * 8 * 64 + (size_t)wv_ * 512 + l;

    f32x4 acc0 = {0.f,0.f,0.f,0.f}, acc1 = acc0, acc2 = acc0, acc3 = acc0;
    float dsum = 0.0f;

    for (int i = 0; i < 4; ++i) {
        const int t = wv_ + 4 * i;
        // scores via SAD
        unsigned accu[16];
#pragma unroll
        for (int kk = 0; kk < 2; ++kk) {
#pragma unroll
            for (int e = 0; e < 8; ++e) {
                uint4 kq[4];
#pragma unroll
                for (int r = 0; r < 4; ++r) kq[r] = kp[(kk * 32 + e) * 4 + r];
                const unsigned* kr = (const unsigned*)kq;
                unsigned s = 0u;
#pragma unroll
                for (int w = 0; w < 16; ++w) s = sad_u8(qv[w], kr[w], s);
                accu[kk * 8 + e] = s;
            }
        }

        // p = exp2(CQ * sad)
        float p[16];
#pragma unroll
        for (int ii = 0; ii < 16; ++ii)
            p[ii] = __builtin_amdgcn_exp2f(CQ * (float)accu[ii]);
        if (t == 15) {  // mask ts >= 1000 (tile-local ts >= 40)
#pragma unroll
            for (int kk = 0; kk < 2; ++kk)
#pragma unroll
                for (int e = 0; e < 8; ++e)
                    if (kk * 32 + (g << 3) + e >= 40) p[kk * 8 + e] = 0.0f;
        }
#pragma unroll
        for (int ii = 0; ii < 16; ++ii) dsum += p[ii];

        // pack p -> bf16 A-fragments (kk=0: e 0..7, kk=1: e 8..15)
        bf16x8 A0 = mkbf(cvt_pk_bf16(p[0], p[1]),  cvt_pk_bf16(p[2], p[3]),
                         cvt_pk_bf16(p[4], p[5]),  cvt_pk_bf16(p[6], p[7]));
        bf16x8 A1 = mkbf(cvt_pk_bf16(p[8], p[9]),  cvt_pk_bf16(p[10], p[11]),
                         cvt_pk_bf16(p[12], p[13]), cvt_pk_bf16(p[14], p[15]));

        // V fragments in two halves of 4 (keeps VGPR under the 64 cap)
        {
            uint4 vf0 = vp[0 * 64], vf1 = vp[1 * 64], vf2 = vp[2 * 64], vf3 = vp[3 * 64];
            acc0 = __builtin_amdgcn_mfma_f32_16x16x32_bf16(A0, bfc(vf0), acc0, 0, 0, 0);
            acc1 = __builtin_amdgcn_mfma_f32_16x16x32_bf16(A0, bfc(vf1), acc1, 0, 0, 0);
            acc2 = __builtin_amdgcn_mfma_f32_16x16x32_bf16(A0, bfc(vf2), acc2, 0, 0, 0);
            acc3 = __builtin_amdgcn_mfma_f32_16x16x32_bf16(A0, bfc(vf3), acc3, 0, 0, 0);
        }
        {
            uint4 vf4 = vp[4 * 64], vf5 = vp[5 * 64], vf6 = vp[6 * 64], vf7 = vp[7 * 64];
            acc0 = __builtin_amdgcn_mfma_f32_16x16x32_bf16(A1, bfc(vf4), acc0, 0, 0, 0);
            acc1 = __builtin_amdgcn_mfma_f32_16x16x32_bf16(A1, bfc(vf5), acc1, 0, 0, 0);
            acc2 = __builtin_amdgcn_mfma_f32_16x16x32_bf16(A1, bfc(vf6), acc2, 0, 0, 0);
            acc3 = __builtin_amdgcn_mfma_f32_16x16x32_bf16(A1, bfc(vf7), acc3, 0, 0, 0);
        }

        kp += 4 * 256;   // skip 4 tiles (64 rows * 4 uint4 each)
        vp += 4 * 512;   // skip 4 tiles (8 entries * 64 lanes each)
    }

    // within-wave denominator reduce over the 4 lane-groups sharing m
    dsum += __shfl_xor(dsum, 16);
    dsum += __shfl_xor(dsum, 32);
    if (l < 16) dred[wv_][l] = dsum;

    // numerators to LDS
#pragma unroll
    for (int j = 0; j < 4; ++j) {
        red[0 * 4 + j][wv_][l] = acc0[j];
        red[1 * 4 + j][wv_][l] = acc1[j];
        red[2 * 4 + j][wv_][l] = acc2[j];
        red[3 * 4 + j][wv_][l] = acc3[j];
    }
    __syncthreads();

    // wave w finalizes accumulator set n=w: value v = w*4+j -> row qt*16+g*4+j, col w*16+m
#pragma unroll
    for (int j = 0; j < 4; ++j) {
        const int v = wv_ * 4 + j;
        float rsum = red[v][0][l] + red[v][1][l] + red[v][2][l] + red[v][3][l];
        const int mm = g * 4 + j;
        float den = 1.0f + dred[0][mm] + dred[1][mm] + dred[2][mm] + dred[3][mm];
        int row = qt * 16 + mm;
        if (row < Tt)
            part[(((size_t)b * Tt + row) * NHh + h) * 64 + wv_ * 16 + m] = rsum / den;
    }
}

// ---------------- Kernel C: head-sum + ReLU + wf projection + residual ----------
__global__ __launch_bounds__(256) void finalize_kernel(
    const float* __restrict__ x, const float* __restrict__ wf,
    const float* __restrict__ part, float* __restrict__ out)
{
    __shared__ float wfs[64][65];
    __shared__ float osh[4][64];
    const int tid = threadIdx.x;
    for (int i = tid; i < 64 * 65; i += 256) wfs[i / 65][i % 65] = wf[i];
    const int wave = tid >> 6, lane = tid & 63;
    const int token = blockIdx.x * 4 + wave;   // 0..7999
    float o = 0.f;
    const float* pt = part + (size_t)token * NHh * Dd;
#pragma unroll
    for (int hh = 0; hh < NHh; ++hh) o += pt[hh * Dd + lane];
    o = fmaxf(o, 0.f);
    osh[wave][lane] = o;
    __syncthreads();
    float acc = wfs[lane][64];    // bias
#pragma unroll 8
    for (int w = 0; w < 64; ++w) acc += wfs[lane][w] * osh[wave][w];
    out[(size_t)token * Dd + lane] = x[(size_t)token * Dd + lane] + acc;
}

extern "C" void kernel_launch(void* const* d_in, const int* in_sizes, int n_in,
                              void* d_out, int out_size, void* d_ws, size_t ws_size,
                              hipStream_t stream)
{
    const float* x  = (const float*)d_in[0];
    const float* wq = (const float*)d_in[1];
    const float* wv = (const float*)d_in[2];
    const float* wk = (const float*)d_in[3];
    const float* wf = (const float*)d_in[4];
    float* out = (float*)d_out;

    char* base = (char*)d_ws;
    float*    part  = (float*)base;                                   // 16,384,000 B
    unsigned* qq8   = (unsigned*)(base + 16384000);                   //  4,194,304 B
    unsigned* kq8   = (unsigned*)(base + 16384000 + 4194304);         //  4,194,304 B
    uint4*    vfrag = (uint4*)(base + 16384000 + 2 * 4194304);        //  8,388,608 B

    prep_kernel<<<dim3(16, 16, Bb), 256, 0, stream>>>(x, wq, wv, wk, qq8, kq8, vfrag);
    attn_kernel<<<dim3(63, NHh, Bb), 256, 0, stream>>>(qq8, kq8, vfrag, part);
    finalize_kernel<<<2000, 256, 0, stream>>>(x, wf, part, out);
}

// Round 4
// 330.272 us; speedup vs baseline: 2.3848x; 2.3848x over previous
//
#include <hip/hip_runtime.h>
#include <math.h>

#define Bb 8
#define Tt 1000
#define TPAD 1024
#define NHh 8
#define Dd 64

typedef short bf16x8 __attribute__((ext_vector_type(8)));
typedef float f32x4 __attribute__((ext_vector_type(4)));

#define QOFF (-0.3f)
#define QSTEP (0.6f / 256.0f)
#define QINV (256.0f / 0.6f)
// p = exp2(CQ * sad)  where score = -(1/8)*STEP*sad
#define CQ (-0.125f * 1.44269504088896341f * QSTEP)

__device__ __forceinline__ unsigned sad_u8(unsigned a, unsigned b, unsigned c) {
#if __has_builtin(__builtin_amdgcn_sad_u8)
    return __builtin_amdgcn_sad_u8(a, b, c);
#else
    unsigned d;
    asm("v_sad_u8 %0, %1, %2, %3" : "=v"(d) : "v"(a), "v"(b), "v"(c));
    return d;
#endif
}

__device__ __forceinline__ unsigned quant8(float v) {
    float t = (v - QOFF) * QINV + 0.5f;
    t = fminf(fmaxf(t, 0.0f), 255.0f);
    return (unsigned)(int)t;
}

__device__ __forceinline__ unsigned cvt_pk_bf16(float lo, float hi) {
    unsigned r;
    asm("v_cvt_pk_bf16_f32 %0, %1, %2" : "=v"(r) : "v"(lo), "v"(hi));
    return r;
}

__device__ __forceinline__ bf16x8 mkbf(unsigned u0, unsigned u1, unsigned u2, unsigned u3) {
    union { unsigned u[4]; bf16x8 v; } x;
    x.u[0] = u0; x.u[1] = u1; x.u[2] = u2; x.u[3] = u3;
    return x.v;
}

__device__ __forceinline__ bf16x8 bfc(uint4 q) {
    union { uint4 q; bf16x8 v; } x; x.q = q; return x.v;
}

// ---------------- Kernel A: prep ----------------
// cb<8: q GEMM -> qq8 (u8, packed 4/dword, [bh][1024][16]dw)  +  k quantize -> kq8 (same layout)
// cb>=8: v GEMM -> vfrag bf16 B-fragment layout [bh][st][kk*4+n][lane] of 16B
__global__ __launch_bounds__(256) void prep_kernel(
    const float* __restrict__ x, const float* __restrict__ wq,
    const float* __restrict__ wv, const float* __restrict__ wk,
    unsigned* __restrict__ qq8, unsigned* __restrict__ kq8,
    uint4* __restrict__ vfrag)
{
    __shared__ float xs[64][68];
    __shared__ float ws[64][65];
    __shared__ float vS[64][68];
    const int tid = threadIdx.x;
    const int st = blockIdx.x;      // 0..15 token tile within (b)
    const int cb = blockIdx.y;      // 0..15
    const int b  = blockIdx.z;
    const bool isQ = (cb < 8);
    const int h = isQ ? cb : (cb - 8);
    const float* W = isQ ? wq : wv;
    const int cBase = h * 64;
    const int bh = b * NHh + h;

#pragma unroll
    for (int i = 0; i < 4; ++i) {
        int f4 = tid + i * 256;
        int r = f4 >> 4, c4 = (f4 & 15) << 2;
        int row = st * 64 + r; if (row >= Tt) row = Tt - 1;
        *(float4*)&xs[r][c4] = *(const float4*)&x[((size_t)b * Tt + row) * 64 + c4];
    }
#pragma unroll
    for (int i = 0; i < 16; ++i) {
        int idx = tid + i * 256;
        int c = idx >> 6, k = idx & 63;
        ws[c][k] = W[(cBase + c) * 65 + k];
    }
    __syncthreads();

    const int rg = tid >> 4, cg = tid & 15;
    const int r0 = rg * 4, c0 = cg * 4;
    float acc[4][4];
#pragma unroll
    for (int j = 0; j < 4; ++j) {
        float bias = W[(cBase + c0 + j) * 65 + 64];
#pragma unroll
        for (int i = 0; i < 4; ++i) acc[i][j] = bias;
    }
    for (int k0 = 0; k0 < 64; k0 += 4) {
        float4 a[4];
#pragma unroll
        for (int i = 0; i < 4; ++i) a[i] = *(const float4*)&xs[r0 + i][k0];
#pragma unroll
        for (int j = 0; j < 4; ++j) {
            float b0 = ws[c0 + j][k0 + 0];
            float b1 = ws[c0 + j][k0 + 1];
            float b2 = ws[c0 + j][k0 + 2];
            float b3 = ws[c0 + j][k0 + 3];
#pragma unroll
            for (int i = 0; i < 4; ++i)
                acc[i][j] += a[i].x * b0 + a[i].y * b1 + a[i].z * b2 + a[i].w * b3;
        }
    }

    if (isQ) {
        // q -> qq8
#pragma unroll
        for (int i = 0; i < 4; ++i) {
            int t = st * 64 + r0 + i;
            unsigned d = 0u;
            if (t < Tt)
                d = quant8(acc[i][0]) | (quant8(acc[i][1]) << 8) |
                    (quant8(acc[i][2]) << 16) | (quant8(acc[i][3]) << 24);
            qq8[((size_t)bh * TPAD + t) * 16 + cg] = d;
        }
        // k = x*wk[h] -> kq8 : thread handles row tid>>2, 16 w's at (tid&3)*16
        {
            const int r = tid >> 2, c4 = tid & 3;
            const int t = st * 64 + r;
            unsigned kd[4];
            if (t < Tt) {
#pragma unroll
                for (int dw = 0; dw < 4; ++dw) {
                    int w = c4 * 16 + dw * 4;
                    float4 wkv = *(const float4*)&wk[h * 64 + w];
                    kd[dw] = quant8(xs[r][w + 0] * wkv.x) |
                             (quant8(xs[r][w + 1] * wkv.y) << 8) |
                             (quant8(xs[r][w + 2] * wkv.z) << 16) |
                             (quant8(xs[r][w + 3] * wkv.w) << 24);
                }
            } else {
                kd[0] = kd[1] = kd[2] = kd[3] = 0u;
            }
            *(uint4*)&kq8[((size_t)bh * TPAD + t) * 16 + c4 * 4] =
                make_uint4(kd[0], kd[1], kd[2], kd[3]);
        }
    } else {
        // v -> vS -> bf16 fragment layout
#pragma unroll
        for (int i = 0; i < 4; ++i) {
            float4 o; o.x = acc[i][0]; o.y = acc[i][1]; o.z = acc[i][2]; o.w = acc[i][3];
            *(float4*)&vS[r0 + i][c0] = o;
        }
        __syncthreads();
#pragma unroll
        for (int e2 = 0; e2 < 2; ++e2) {
            int ent = tid + e2 * 256;       // 0..511 = kk*256 + n*64 + lane
            int kk = ent >> 8, rem = ent & 255, n = rem >> 6, lane = rem & 63;
            int ts = kk * 32 + ((lane >> 4) << 3);
            int w  = n * 16 + (lane & 15);
            unsigned o[4];
#pragma unroll
            for (int pr = 0; pr < 4; ++pr) {
                int t0 = st * 64 + ts + pr * 2;
                float lo = (t0 < Tt)     ? vS[ts + pr * 2][w]     : 0.0f;
                float hi = (t0 + 1 < Tt) ? vS[ts + pr * 2 + 1][w] : 0.0f;
                o[pr] = cvt_pk_bf16(lo, hi);
            }
            vfrag[(((size_t)bh * 16 + st) * 8 + (kk * 4 + n)) * 64 + lane] =
                make_uint4(o[0], o[1], o[2], o[3]);
        }
    }
}

// ---------------- Kernel B: attention, 4 waves/block, LDS cross-wave reduce ----------------
// Wave w handles source tiles {w, w+4, w+8, w+12}; lane l: P rows tq = qt*16 + (l&15);
// ts = tile*64 + kk*32 + (l>>4)*8 + e (A-frag layout). Numerators+denoms reduced via LDS.
// NOTE: min-waves/EU = 4 (128 VGPR cap). Round 3 used 8 (64 cap) -> spill -> 3.2 GB scratch traffic.
__global__ __launch_bounds__(256, 4) void attn_kernel(
    const unsigned* __restrict__ qq8, const unsigned* __restrict__ kq8,
    const uint4* __restrict__ vfrag, float* __restrict__ part)
{
    __shared__ float red[16][4][64];   // [v=n*4+j][wave][lane] — lane-major: conflict-free
    __shared__ float dred[4][16];      // [wave][m]

    const int tid = threadIdx.x;
    const int wv_ = tid >> 6;          // wave 0..3
    const int l   = tid & 63;
    const int qt  = blockIdx.x;        // 0..62
    const int h   = blockIdx.y, b = blockIdx.z;
    const int bh  = b * NHh + h;
    const int g   = l >> 4;            // 0..3
    const int m   = l & 15;

    // q row (16 dwords = 64 u8)
    unsigned qv[16];
    {
        const uint4* qp = (const uint4*)(qq8 + ((size_t)bh * TPAD + qt * 16 + m) * 16);
        *(uint4*)&qv[0]  = qp[0];
        *(uint4*)&qv[4]  = qp[1];
        *(uint4*)&qv[8]  = qp[2];
        *(uint4*)&qv[12] = qp[3];
    }

    // k pointer: start at wave's first tile, group g's first row (uint4 units; row = 4 uint4)
    const uint4* kp = (const uint4*)(kq8 + (size_t)bh * TPAD * 16) + (size_t)wv_ * 256 + g * 8 * 4;
    // v fragments: entry lane l of wave's first tile; entries stride 64, tiles stride 512
    const uint4* vp = vfrag + (size_t)bh * 16 * 8 * 64 + (size_t)wv_ * 512 + l;

    f32x4 acc0 = {0.f,0.f,0.f,0.f}, acc1 = acc0, acc2 = acc0, acc3 = acc0;
    float dsum = 0.0f;

    for (int i = 0; i < 4; ++i) {
        const int t = wv_ + 4 * i;
        // scores via SAD
        unsigned accu[16];
#pragma unroll
        for (int kk = 0; kk < 2; ++kk) {
#pragma unroll
            for (int e = 0; e < 8; ++e) {
                uint4 kq[4];
#pragma unroll
                for (int r = 0; r < 4; ++r) kq[r] = kp[(kk * 32 + e) * 4 + r];
                const unsigned* kr = (const unsigned*)kq;
                unsigned s = 0u;
#pragma unroll
                for (int w = 0; w < 16; ++w) s = sad_u8(qv[w], kr[w], s);
                accu[kk * 8 + e] = s;
            }
        }

        // p = exp2(CQ * sad)
        float p[16];
#pragma unroll
        for (int ii = 0; ii < 16; ++ii)
            p[ii] = __builtin_amdgcn_exp2f(CQ * (float)accu[ii]);
        if (t == 15) {  // mask ts >= 1000 (tile-local ts >= 40)
#pragma unroll
            for (int kk = 0; kk < 2; ++kk)
#pragma unroll
                for (int e = 0; e < 8; ++e)
                    if (kk * 32 + (g << 3) + e >= 40) p[kk * 8 + e] = 0.0f;
        }
#pragma unroll
        for (int ii = 0; ii < 16; ++ii) dsum += p[ii];

        // pack p -> bf16 A-fragments (kk=0: e 0..7, kk=1: e 8..15)
        bf16x8 A0 = mkbf(cvt_pk_bf16(p[0], p[1]),  cvt_pk_bf16(p[2], p[3]),
                         cvt_pk_bf16(p[4], p[5]),  cvt_pk_bf16(p[6], p[7]));
        bf16x8 A1 = mkbf(cvt_pk_bf16(p[8], p[9]),  cvt_pk_bf16(p[10], p[11]),
                         cvt_pk_bf16(p[12], p[13]), cvt_pk_bf16(p[14], p[15]));

        // V fragments in two halves of 4 (limits live uint4 regs)
        {
            uint4 vf0 = vp[0 * 64], vf1 = vp[1 * 64], vf2 = vp[2 * 64], vf3 = vp[3 * 64];
            acc0 = __builtin_amdgcn_mfma_f32_16x16x32_bf16(A0, bfc(vf0), acc0, 0, 0, 0);
            acc1 = __builtin_amdgcn_mfma_f32_16x16x32_bf16(A0, bfc(vf1), acc1, 0, 0, 0);
            acc2 = __builtin_amdgcn_mfma_f32_16x16x32_bf16(A0, bfc(vf2), acc2, 0, 0, 0);
            acc3 = __builtin_amdgcn_mfma_f32_16x16x32_bf16(A0, bfc(vf3), acc3, 0, 0, 0);
        }
        {
            uint4 vf4 = vp[4 * 64], vf5 = vp[5 * 64], vf6 = vp[6 * 64], vf7 = vp[7 * 64];
            acc0 = __builtin_amdgcn_mfma_f32_16x16x32_bf16(A1, bfc(vf4), acc0, 0, 0, 0);
            acc1 = __builtin_amdgcn_mfma_f32_16x16x32_bf16(A1, bfc(vf5), acc1, 0, 0, 0);
            acc2 = __builtin_amdgcn_mfma_f32_16x16x32_bf16(A1, bfc(vf6), acc2, 0, 0, 0);
            acc3 = __builtin_amdgcn_mfma_f32_16x16x32_bf16(A1, bfc(vf7), acc3, 0, 0, 0);
        }

        kp += 4 * 256;   // skip 4 tiles (64 rows * 4 uint4 each)
        vp += 4 * 512;   // skip 4 tiles (8 entries * 64 lanes each)
    }

    // within-wave denominator reduce over the 4 lane-groups sharing m
    dsum += __shfl_xor(dsum, 16);
    dsum += __shfl_xor(dsum, 32);
    if (l < 16) dred[wv_][l] = dsum;

    // numerators to LDS
#pragma unroll
    for (int j = 0; j < 4; ++j) {
        red[0 * 4 + j][wv_][l] = acc0[j];
        red[1 * 4 + j][wv_][l] = acc1[j];
        red[2 * 4 + j][wv_][l] = acc2[j];
        red[3 * 4 + j][wv_][l] = acc3[j];
    }
    __syncthreads();

    // wave w finalizes accumulator set n=w: value v = w*4+j -> row qt*16+g*4+j, col w*16+m
#pragma unroll
    for (int j = 0; j < 4; ++j) {
        const int v = wv_ * 4 + j;
        float rsum = red[v][0][l] + red[v][1][l] + red[v][2][l] + red[v][3][l];
        const int mm = g * 4 + j;
        float den = 1.0f + dred[0][mm] + dred[1][mm] + dred[2][mm] + dred[3][mm];
        int row = qt * 16 + mm;
        if (row < Tt)
            part[(((size_t)b * Tt + row) * NHh + h) * 64 + wv_ * 16 + m] = rsum / den;
    }
}

// ---------------- Kernel C: head-sum + ReLU + wf projection + residual ----------
__global__ __launch_bounds__(256) void finalize_kernel(
    const float* __restrict__ x, const float* __restrict__ wf,
    const float* __restrict__ part, float* __restrict__ out)
{
    __shared__ float wfs[64][65];
    __shared__ float osh[4][64];
    const int tid = threadIdx.x;
    for (int i = tid; i < 64 * 65; i += 256) wfs[i / 65][i % 65] = wf[i];
    const int wave = tid >> 6, lane = tid & 63;
    const int token = blockIdx.x * 4 + wave;   // 0..7999
    float o = 0.f;
    const float* pt = part + (size_t)token * NHh * Dd;
#pragma unroll
    for (int hh = 0; hh < NHh; ++hh) o += pt[hh * Dd + lane];
    o = fmaxf(o, 0.f);
    osh[wave][lane] = o;
    __syncthreads();
    float acc = wfs[lane][64];    // bias
#pragma unroll 8
    for (int w = 0; w < 64; ++w) acc += wfs[lane][w] * osh[wave][w];
    out[(size_t)token * Dd + lane] = x[(size_t)token * Dd + lane] + acc;
}

extern "C" void kernel_launch(void* const* d_in, const int* in_sizes, int n_in,
                              void* d_out, int out_size, void* d_ws, size_t ws_size,
                              hipStream_t stream)
{
    const float* x  = (const float*)d_in[0];
    const float* wq = (const float*)d_in[1];
    const float* wv = (const float*)d_in[2];
    const float* wk = (const float*)d_in[3];
    const float* wf = (const float*)d_in[4];
    float* out = (float*)d_out;

    char* base = (char*)d_ws;
    float*    part  = (float*)base;                                   // 16,384,000 B
    unsigned* qq8   = (unsigned*)(base + 16384000);                   //  4,194,304 B
    unsigned* kq8   = (unsigned*)(base + 16384000 + 4194304);         //  4,194,304 B
    uint4*    vfrag = (uint4*)(base + 16384000 + 2 * 4194304);        //  8,388,608 B

    prep_kernel<<<dim3(16, 16, Bb), 256, 0, stream>>>(x, wq, wv, wk, qq8, kq8, vfrag);
    attn_kernel<<<dim3(63, NHh, Bb), 256, 0, stream>>>(qq8, kq8, vfrag, part);
    finalize_kernel<<<2000, 256, 0, stream>>>(x, wf, part, out);
}

// Round 5
// 171.495 us; speedup vs baseline: 4.5927x; 1.9258x over previous
//
#include <hip/hip_runtime.h>
#include <math.h>

#define Bb 8
#define Tt 1000
#define TPAD 1024
#define NHh 8
#define Dd 64

typedef short bf16x8 __attribute__((ext_vector_type(8)));
typedef float f32x4 __attribute__((ext_vector_type(4)));

#define QOFF (-0.3f)
#define QSTEP (0.6f / 256.0f)
#define QINV (256.0f / 0.6f)
// p = exp2(CQ * sad)  where score = -(1/8)*STEP*sad
#define CQ (-0.125f * 1.44269504088896341f * QSTEP)

__device__ __forceinline__ unsigned sad_u8(unsigned a, unsigned b, unsigned c) {
#if __has_builtin(__builtin_amdgcn_sad_u8)
    return __builtin_amdgcn_sad_u8(a, b, c);
#else
    unsigned d;
    asm("v_sad_u8 %0, %1, %2, %3" : "=v"(d) : "v"(a), "v"(b), "v"(c));
    return d;
#endif
}

__device__ __forceinline__ unsigned quant8(float v) {
    float t = (v - QOFF) * QINV + 0.5f;
    t = fminf(fmaxf(t, 0.0f), 255.0f);
    return (unsigned)(int)t;
}

__device__ __forceinline__ unsigned cvt_pk_bf16(float lo, float hi) {
    unsigned r;
    asm("v_cvt_pk_bf16_f32 %0, %1, %2" : "=v"(r) : "v"(lo), "v"(hi));
    return r;
}

__device__ __forceinline__ bf16x8 mkbf(unsigned u0, unsigned u1, unsigned u2, unsigned u3) {
    union { unsigned u[4]; bf16x8 v; } x;
    x.u[0] = u0; x.u[1] = u1; x.u[2] = u2; x.u[3] = u3;
    return x.v;
}

__device__ __forceinline__ bf16x8 bfc(uint4 q) {
    union { uint4 q; bf16x8 v; } x; x.q = q; return x.v;
}

// ---------------- Kernel A: prep ----------------
// cb<8: q GEMM -> qq8 (u8, packed 4/dword, [bh][1024][16]dw)  +  k quantize -> kq8 (same layout)
// cb>=8: v GEMM -> vfrag bf16 B-fragment layout [bh][st][kk*4+n][lane] of 16B
__global__ __launch_bounds__(256) void prep_kernel(
    const float* __restrict__ x, const float* __restrict__ wq,
    const float* __restrict__ wv, const float* __restrict__ wk,
    unsigned* __restrict__ qq8, unsigned* __restrict__ kq8,
    uint4* __restrict__ vfrag)
{
    __shared__ float xs[64][68];
    __shared__ float ws[64][65];
    __shared__ float vS[64][68];
    const int tid = threadIdx.x;
    const int st = blockIdx.x;      // 0..15 token tile within (b)
    const int cb = blockIdx.y;      // 0..15
    const int b  = blockIdx.z;
    const bool isQ = (cb < 8);
    const int h = isQ ? cb : (cb - 8);
    const float* W = isQ ? wq : wv;
    const int cBase = h * 64;
    const int bh = b * NHh + h;

#pragma unroll
    for (int i = 0; i < 4; ++i) {
        int f4 = tid + i * 256;
        int r = f4 >> 4, c4 = (f4 & 15) << 2;
        int row = st * 64 + r; if (row >= Tt) row = Tt - 1;
        *(float4*)&xs[r][c4] = *(const float4*)&x[((size_t)b * Tt + row) * 64 + c4];
    }
#pragma unroll
    for (int i = 0; i < 16; ++i) {
        int idx = tid + i * 256;
        int c = idx >> 6, k = idx & 63;
        ws[c][k] = W[(cBase + c) * 65 + k];
    }
    __syncthreads();

    const int rg = tid >> 4, cg = tid & 15;
    const int r0 = rg * 4, c0 = cg * 4;
    float acc[4][4];
#pragma unroll
    for (int j = 0; j < 4; ++j) {
        float bias = W[(cBase + c0 + j) * 65 + 64];
#pragma unroll
        for (int i = 0; i < 4; ++i) acc[i][j] = bias;
    }
    for (int k0 = 0; k0 < 64; k0 += 4) {
        float4 a[4];
#pragma unroll
        for (int i = 0; i < 4; ++i) a[i] = *(const float4*)&xs[r0 + i][k0];
#pragma unroll
        for (int j = 0; j < 4; ++j) {
            float b0 = ws[c0 + j][k0 + 0];
            float b1 = ws[c0 + j][k0 + 1];
            float b2 = ws[c0 + j][k0 + 2];
            float b3 = ws[c0 + j][k0 + 3];
#pragma unroll
            for (int i = 0; i < 4; ++i)
                acc[i][j] += a[i].x * b0 + a[i].y * b1 + a[i].z * b2 + a[i].w * b3;
        }
    }

    if (isQ) {
        // q -> qq8
#pragma unroll
        for (int i = 0; i < 4; ++i) {
            int t = st * 64 + r0 + i;
            unsigned d = 0u;
            if (t < Tt)
                d = quant8(acc[i][0]) | (quant8(acc[i][1]) << 8) |
                    (quant8(acc[i][2]) << 16) | (quant8(acc[i][3]) << 24);
            qq8[((size_t)bh * TPAD + t) * 16 + cg] = d;
        }
        // k = x*wk[h] -> kq8 : thread handles row tid>>2, 16 w's at (tid&3)*16
        {
            const int r = tid >> 2, c4 = tid & 3;
            const int t = st * 64 + r;
            unsigned kd[4];
            if (t < Tt) {
#pragma unroll
                for (int dw = 0; dw < 4; ++dw) {
                    int w = c4 * 16 + dw * 4;
                    float4 wkv = *(const float4*)&wk[h * 64 + w];
                    kd[dw] = quant8(xs[r][w + 0] * wkv.x) |
                             (quant8(xs[r][w + 1] * wkv.y) << 8) |
                             (quant8(xs[r][w + 2] * wkv.z) << 16) |
                             (quant8(xs[r][w + 3] * wkv.w) << 24);
                }
            } else {
                kd[0] = kd[1] = kd[2] = kd[3] = 0u;
            }
            *(uint4*)&kq8[((size_t)bh * TPAD + t) * 16 + c4 * 4] =
                make_uint4(kd[0], kd[1], kd[2], kd[3]);
        }
    } else {
        // v -> vS -> bf16 fragment layout
#pragma unroll
        for (int i = 0; i < 4; ++i) {
            float4 o; o.x = acc[i][0]; o.y = acc[i][1]; o.z = acc[i][2]; o.w = acc[i][3];
            *(float4*)&vS[r0 + i][c0] = o;
        }
        __syncthreads();
#pragma unroll
        for (int e2 = 0; e2 < 2; ++e2) {
            int ent = tid + e2 * 256;       // 0..511 = kk*256 + n*64 + lane
            int kk = ent >> 8, rem = ent & 255, n = rem >> 6, lane = rem & 63;
            int ts = kk * 32 + ((lane >> 4) << 3);
            int w  = n * 16 + (lane & 15);
            unsigned o[4];
#pragma unroll
            for (int pr = 0; pr < 4; ++pr) {
                int t0 = st * 64 + ts + pr * 2;
                float lo = (t0 < Tt)     ? vS[ts + pr * 2][w]     : 0.0f;
                float hi = (t0 + 1 < Tt) ? vS[ts + pr * 2 + 1][w] : 0.0f;
                o[pr] = cvt_pk_bf16(lo, hi);
            }
            vfrag[(((size_t)bh * 16 + st) * 8 + (kk * 4 + n)) * 64 + lane] =
                make_uint4(o[0], o[1], o[2], o[3]);
        }
    }
}

// ---------------- Kernel B: attention, 4 waves/block, LDS cross-wave reduce ----------------
// Wave w handles source tiles {w, w+4, w+8, w+12}; lane l: P rows tq = qt*16 + (l&15);
// ts = tile*64 + kk*32 + (l>>4)*8 + e (A-frag layout). Numerators+denoms reduced via LDS.
// NOTE: no min-waves cap — rounds 3/4 proved any cap forces arch/acc split + scratch spill
// (794 MB WRITE_SIZE). Tile loop kept unroll-1 so V-loads aren't hoisted across iterations.
__global__ __launch_bounds__(256) void attn_kernel(
    const unsigned* __restrict__ qq8, const unsigned* __restrict__ kq8,
    const uint4* __restrict__ vfrag, float* __restrict__ part)
{
    __shared__ float red[16][4][64];   // [v=n*4+j][wave][lane] — lane-major: conflict-free
    __shared__ float dred[4][16];      // [wave][m]

    const int tid = threadIdx.x;
    const int wv_ = tid >> 6;          // wave 0..3
    const int l   = tid & 63;
    const int qt  = blockIdx.x;        // 0..62
    const int h   = blockIdx.y, b = blockIdx.z;
    const int bh  = b * NHh + h;
    const int g   = l >> 4;            // 0..3
    const int m   = l & 15;

    // q row (16 dwords = 64 u8)
    unsigned qv[16];
    {
        const uint4* qp = (const uint4*)(qq8 + ((size_t)bh * TPAD + qt * 16 + m) * 16);
        *(uint4*)&qv[0]  = qp[0];
        *(uint4*)&qv[4]  = qp[1];
        *(uint4*)&qv[8]  = qp[2];
        *(uint4*)&qv[12] = qp[3];
    }

    // k pointer: start at wave's first tile, group g's first row (uint4 units; row = 4 uint4)
    const uint4* kp = (const uint4*)(kq8 + (size_t)bh * TPAD * 16) + (size_t)wv_ * 256 + g * 8 * 4;
    // v fragments: entry lane l of wave's first tile; entries stride 64, tiles stride 512
    const uint4* vp = vfrag + (size_t)bh * 16 * 8 * 64 + (size_t)wv_ * 512 + l;

    f32x4 acc0 = {0.f,0.f,0.f,0.f}, acc1 = acc0, acc2 = acc0, acc3 = acc0;
    float dsum = 0.0f;

#pragma unroll 1
    for (int i = 0; i < 4; ++i) {
        const int t = wv_ + 4 * i;
        bf16x8 A0, A1;

        // ---- kk = 0 half: ts_local 0..31, never masked (max g*8+e = 31 < 40)
        {
            unsigned accu[8];
#pragma unroll
            for (int e = 0; e < 8; ++e) {
                uint4 kq0 = kp[e * 4 + 0];
                uint4 kq1 = kp[e * 4 + 1];
                uint4 kq2 = kp[e * 4 + 2];
                uint4 kq3 = kp[e * 4 + 3];
                const unsigned* k0 = (const unsigned*)&kq0;
                const unsigned* k1 = (const unsigned*)&kq1;
                const unsigned* k2 = (const unsigned*)&kq2;
                const unsigned* k3 = (const unsigned*)&kq3;
                unsigned s = 0u;
#pragma unroll
                for (int w = 0; w < 4; ++w) s = sad_u8(qv[w],      k0[w], s);
#pragma unroll
                for (int w = 0; w < 4; ++w) s = sad_u8(qv[4 + w],  k1[w], s);
#pragma unroll
                for (int w = 0; w < 4; ++w) s = sad_u8(qv[8 + w],  k2[w], s);
#pragma unroll
                for (int w = 0; w < 4; ++w) s = sad_u8(qv[12 + w], k3[w], s);
                accu[e] = s;
            }
            float p[8];
#pragma unroll
            for (int e = 0; e < 8; ++e) {
                p[e] = __builtin_amdgcn_exp2f(CQ * (float)accu[e]);
                dsum += p[e];
            }
            A0 = mkbf(cvt_pk_bf16(p[0], p[1]), cvt_pk_bf16(p[2], p[3]),
                      cvt_pk_bf16(p[4], p[5]), cvt_pk_bf16(p[6], p[7]));
        }

        // ---- kk = 1 half: ts_local 32..63; tile 15 masks g>=1 entirely
        {
            unsigned accu[8];
#pragma unroll
            for (int e = 0; e < 8; ++e) {
                uint4 kq0 = kp[(32 + e) * 4 + 0];
                uint4 kq1 = kp[(32 + e) * 4 + 1];
                uint4 kq2 = kp[(32 + e) * 4 + 2];
                uint4 kq3 = kp[(32 + e) * 4 + 3];
                const unsigned* k0 = (const unsigned*)&kq0;
                const unsigned* k1 = (const unsigned*)&kq1;
                const unsigned* k2 = (const unsigned*)&kq2;
                const unsigned* k3 = (const unsigned*)&kq3;
                unsigned s = 0u;
#pragma unroll
                for (int w = 0; w < 4; ++w) s = sad_u8(qv[w],      k0[w], s);
#pragma unroll
                for (int w = 0; w < 4; ++w) s = sad_u8(qv[4 + w],  k1[w], s);
#pragma unroll
                for (int w = 0; w < 4; ++w) s = sad_u8(qv[8 + w],  k2[w], s);
#pragma unroll
                for (int w = 0; w < 4; ++w) s = sad_u8(qv[12 + w], k3[w], s);
                accu[e] = s;
            }
            const bool maskall = (t == 15) && (g >= 1);
            float p[8];
#pragma unroll
            for (int e = 0; e < 8; ++e) {
                p[e] = maskall ? 0.0f : __builtin_amdgcn_exp2f(CQ * (float)accu[e]);
                dsum += p[e];
            }
            A1 = mkbf(cvt_pk_bf16(p[0], p[1]), cvt_pk_bf16(p[2], p[3]),
                      cvt_pk_bf16(p[4], p[5]), cvt_pk_bf16(p[6], p[7]));
        }

        // V fragments in two halves of 4 (limits live uint4 regs)
        {
            uint4 vf0 = vp[0 * 64], vf1 = vp[1 * 64], vf2 = vp[2 * 64], vf3 = vp[3 * 64];
            acc0 = __builtin_amdgcn_mfma_f32_16x16x32_bf16(A0, bfc(vf0), acc0, 0, 0, 0);
            acc1 = __builtin_amdgcn_mfma_f32_16x16x32_bf16(A0, bfc(vf1), acc1, 0, 0, 0);
            acc2 = __builtin_amdgcn_mfma_f32_16x16x32_bf16(A0, bfc(vf2), acc2, 0, 0, 0);
            acc3 = __builtin_amdgcn_mfma_f32_16x16x32_bf16(A0, bfc(vf3), acc3, 0, 0, 0);
        }
        {
            uint4 vf4 = vp[4 * 64], vf5 = vp[5 * 64], vf6 = vp[6 * 64], vf7 = vp[7 * 64];
            acc0 = __builtin_amdgcn_mfma_f32_16x16x32_bf16(A1, bfc(vf4), acc0, 0, 0, 0);
            acc1 = __builtin_amdgcn_mfma_f32_16x16x32_bf16(A1, bfc(vf5), acc1, 0, 0, 0);
            acc2 = __builtin_amdgcn_mfma_f32_16x16x32_bf16(A1, bfc(vf6), acc2, 0, 0, 0);
            acc3 = __builtin_amdgcn_mfma_f32_16x16x32_bf16(A1, bfc(vf7), acc3, 0, 0, 0);
        }

        kp += 4 * 256;   // skip 4 tiles (64 rows * 4 uint4 each)
        vp += 4 * 512;   // skip 4 tiles (8 entries * 64 lanes each)
    }

    // within-wave denominator reduce over the 4 lane-groups sharing m
    dsum += __shfl_xor(dsum, 16);
    dsum += __shfl_xor(dsum, 32);
    if (l < 16) dred[wv_][l] = dsum;

    // numerators to LDS
#pragma unroll
    for (int j = 0; j < 4; ++j) {
        red[0 * 4 + j][wv_][l] = acc0[j];
        red[1 * 4 + j][wv_][l] = acc1[j];
        red[2 * 4 + j][wv_][l] = acc2[j];
        red[3 * 4 + j][wv_][l] = acc3[j];
    }
    __syncthreads();

    // wave w finalizes accumulator set n=w: value v = w*4+j -> row qt*16+g*4+j, col w*16+m
#pragma unroll
    for (int j = 0; j < 4; ++j) {
        const int v = wv_ * 4 + j;
        float rsum = red[v][0][l] + red[v][1][l] + red[v][2][l] + red[v][3][l];
        const int mm = g * 4 + j;
        float den = 1.0f + dred[0][mm] + dred[1][mm] + dred[2][mm] + dred[3][mm];
        int row = qt * 16 + mm;
        if (row < Tt)
            part[(((size_t)b * Tt + row) * NHh + h) * 64 + wv_ * 16 + m] = rsum / den;
    }
}

// ---------------- Kernel C: head-sum + ReLU + wf projection + residual ----------
__global__ __launch_bounds__(256) void finalize_kernel(
    const float* __restrict__ x, const float* __restrict__ wf,
    const float* __restrict__ part, float* __restrict__ out)
{
    __shared__ float wfs[64][65];
    __shared__ float osh[4][64];
    const int tid = threadIdx.x;
    for (int i = tid; i < 64 * 65; i += 256) wfs[i / 65][i % 65] = wf[i];
    const int wave = tid >> 6, lane = tid & 63;
    const int token = blockIdx.x * 4 + wave;   // 0..7999
    float o = 0.f;
    const float* pt = part + (size_t)token * NHh * Dd;
#pragma unroll
    for (int hh = 0; hh < NHh; ++hh) o += pt[hh * Dd + lane];
    o = fmaxf(o, 0.f);
    osh[wave][lane] = o;
    __syncthreads();
    float acc = wfs[lane][64];    // bias
#pragma unroll 8
    for (int w = 0; w < 64; ++w) acc += wfs[lane][w] * osh[wave][w];
    out[(size_t)token * Dd + lane] = x[(size_t)token * Dd + lane] + acc;
}

extern "C" void kernel_launch(void* const* d_in, const int* in_sizes, int n_in,
                              void* d_out, int out_size, void* d_ws, size_t ws_size,
                              hipStream_t stream)
{
    const float* x  = (const float*)d_in[0];
    const float* wq = (const float*)d_in[1];
    const float* wv = (const float*)d_in[2];
    const float* wk = (const float*)d_in[3];
    const float* wf = (const float*)d_in[4];
    float* out = (float*)d_out;

    char* base = (char*)d_ws;
    float*    part  = (float*)base;                                   // 16,384,000 B
    unsigned* qq8   = (unsigned*)(base + 16384000);                   //  4,194,304 B
    unsigned* kq8   = (unsigned*)(base + 16384000 + 4194304);         //  4,194,304 B
    uint4*    vfrag = (uint4*)(base + 16384000 + 2 * 4194304);        //  8,388,608 B

    prep_kernel<<<dim3(16, 16, Bb), 256, 0, stream>>>(x, wq, wv, wk, qq8, kq8, vfrag);
    attn_kernel<<<dim3(63, NHh, Bb), 256, 0, stream>>>(qq8, kq8, vfrag, part);
    finalize_kernel<<<2000, 256, 0, stream>>>(x, wf, part, out);
}

// Round 6
// 95.803 us; speedup vs baseline: 8.2212x; 1.7901x over previous
//
#include <hip/hip_runtime.h>
#include <math.h>

#define Bb 8
#define Tt 1000
#define TPAD 1024
#define NHh 8
#define Dd 64

typedef short bf16x8 __attribute__((ext_vector_type(8)));
typedef float f32x4 __attribute__((ext_vector_type(4)));

#define QOFF (-0.3f)
#define QSTEP (0.6f / 256.0f)
#define QINV (256.0f / 0.6f)
// p = exp2(CQ * sad)  where score = -(1/8)*STEP*sad
#define CQ (-0.125f * 1.44269504088896341f * QSTEP)

__device__ __forceinline__ unsigned sad_u8(unsigned a, unsigned b, unsigned c) {
#if __has_builtin(__builtin_amdgcn_sad_u8)
    return __builtin_amdgcn_sad_u8(a, b, c);
#else
    unsigned d;
    asm("v_sad_u8 %0, %1, %2, %3" : "=v"(d) : "v"(a), "v"(b), "v"(c));
    return d;
#endif
}

__device__ __forceinline__ unsigned quant8(float v) {
    float t = (v - QOFF) * QINV + 0.5f;
    t = fminf(fmaxf(t, 0.0f), 255.0f);
    return (unsigned)(int)t;
}

__device__ __forceinline__ unsigned cvt_pk_bf16(float lo, float hi) {
    unsigned r;
    asm("v_cvt_pk_bf16_f32 %0, %1, %2" : "=v"(r) : "v"(lo), "v"(hi));
    return r;
}

__device__ __forceinline__ bf16x8 mkbf(unsigned u0, unsigned u1, unsigned u2, unsigned u3) {
    union { unsigned u[4]; bf16x8 v; } x;
    x.u[0] = u0; x.u[1] = u1; x.u[2] = u2; x.u[3] = u3;
    return x.v;
}

__device__ __forceinline__ bf16x8 bfc(uint4 q) {
    union { uint4 q; bf16x8 v; } x; x.q = q; return x.v;
}

// ---------------- Kernel A: prep ----------------
// cb<8: q GEMM -> qq8 (u8, packed 4/dword, [bh][1024][16]dw)  +  k quantize -> kq8 (same layout)
// cb>=8: v GEMM -> vfrag bf16 B-fragment layout [bh][st][kk*4+n][lane] of 16B
__global__ __launch_bounds__(256) void prep_kernel(
    const float* __restrict__ x, const float* __restrict__ wq,
    const float* __restrict__ wv, const float* __restrict__ wk,
    unsigned* __restrict__ qq8, unsigned* __restrict__ kq8,
    uint4* __restrict__ vfrag)
{
    __shared__ float xs[64][68];
    __shared__ float ws[64][65];
    __shared__ float vS[64][68];
    const int tid = threadIdx.x;
    const int st = blockIdx.x;      // 0..15 token tile within (b)
    const int cb = blockIdx.y;      // 0..15
    const int b  = blockIdx.z;
    const bool isQ = (cb < 8);
    const int h = isQ ? cb : (cb - 8);
    const float* W = isQ ? wq : wv;
    const int cBase = h * 64;
    const int bh = b * NHh + h;

#pragma unroll
    for (int i = 0; i < 4; ++i) {
        int f4 = tid + i * 256;
        int r = f4 >> 4, c4 = (f4 & 15) << 2;
        int row = st * 64 + r; if (row >= Tt) row = Tt - 1;
        *(float4*)&xs[r][c4] = *(const float4*)&x[((size_t)b * Tt + row) * 64 + c4];
    }
#pragma unroll
    for (int i = 0; i < 16; ++i) {
        int idx = tid + i * 256;
        int c = idx >> 6, k = idx & 63;
        ws[c][k] = W[(cBase + c) * 65 + k];
    }
    __syncthreads();

    const int rg = tid >> 4, cg = tid & 15;
    const int r0 = rg * 4, c0 = cg * 4;
    float acc[4][4];
#pragma unroll
    for (int j = 0; j < 4; ++j) {
        float bias = W[(cBase + c0 + j) * 65 + 64];
#pragma unroll
        for (int i = 0; i < 4; ++i) acc[i][j] = bias;
    }
    for (int k0 = 0; k0 < 64; k0 += 4) {
        float4 a[4];
#pragma unroll
        for (int i = 0; i < 4; ++i) a[i] = *(const float4*)&xs[r0 + i][k0];
#pragma unroll
        for (int j = 0; j < 4; ++j) {
            float b0 = ws[c0 + j][k0 + 0];
            float b1 = ws[c0 + j][k0 + 1];
            float b2 = ws[c0 + j][k0 + 2];
            float b3 = ws[c0 + j][k0 + 3];
#pragma unroll
            for (int i = 0; i < 4; ++i)
                acc[i][j] += a[i].x * b0 + a[i].y * b1 + a[i].z * b2 + a[i].w * b3;
        }
    }

    if (isQ) {
        // q -> qq8
#pragma unroll
        for (int i = 0; i < 4; ++i) {
            int t = st * 64 + r0 + i;
            unsigned d = 0u;
            if (t < Tt)
                d = quant8(acc[i][0]) | (quant8(acc[i][1]) << 8) |
                    (quant8(acc[i][2]) << 16) | (quant8(acc[i][3]) << 24);
            qq8[((size_t)bh * TPAD + t) * 16 + cg] = d;
        }
        // k = x*wk[h] -> kq8 : thread handles row tid>>2, 16 w's at (tid&3)*16
        {
            const int r = tid >> 2, c4 = tid & 3;
            const int t = st * 64 + r;
            unsigned kd[4];
            if (t < Tt) {
#pragma unroll
                for (int dw = 0; dw < 4; ++dw) {
                    int w = c4 * 16 + dw * 4;
                    float4 wkv = *(const float4*)&wk[h * 64 + w];
                    kd[dw] = quant8(xs[r][w + 0] * wkv.x) |
                             (quant8(xs[r][w + 1] * wkv.y) << 8) |
                             (quant8(xs[r][w + 2] * wkv.z) << 16) |
                             (quant8(xs[r][w + 3] * wkv.w) << 24);
                }
            } else {
                kd[0] = kd[1] = kd[2] = kd[3] = 0u;
            }
            *(uint4*)&kq8[((size_t)bh * TPAD + t) * 16 + c4 * 4] =
                make_uint4(kd[0], kd[1], kd[2], kd[3]);
        }
    } else {
        // v -> vS -> bf16 fragment layout
#pragma unroll
        for (int i = 0; i < 4; ++i) {
            float4 o; o.x = acc[i][0]; o.y = acc[i][1]; o.z = acc[i][2]; o.w = acc[i][3];
            *(float4*)&vS[r0 + i][c0] = o;
        }
        __syncthreads();
#pragma unroll
        for (int e2 = 0; e2 < 2; ++e2) {
            int ent = tid + e2 * 256;       // 0..511 = kk*256 + n*64 + lane
            int kk = ent >> 8, rem = ent & 255, n = rem >> 6, lane = rem & 63;
            int ts = kk * 32 + ((lane >> 4) << 3);
            int w  = n * 16 + (lane & 15);
            unsigned o[4];
#pragma unroll
            for (int pr = 0; pr < 4; ++pr) {
                int t0 = st * 64 + ts + pr * 2;
                float lo = (t0 < Tt)     ? vS[ts + pr * 2][w]     : 0.0f;
                float hi = (t0 + 1 < Tt) ? vS[ts + pr * 2 + 1][w] : 0.0f;
                o[pr] = cvt_pk_bf16(lo, hi);
            }
            vfrag[(((size_t)bh * 16 + st) * 8 + (kk * 4 + n)) * 64 + lane] =
                make_uint4(o[0], o[1], o[2], o[3]);
        }
    }
}

// ---------------- Kernel B: attention, LDS-staged double-buffered tiles ----------------
// Block = 64 q-rows (qt*64..qt*64+63), 4 waves; wave w owns q-rows qt*64 + w*16 + (0..15).
// All 4 waves share each source tile staged in LDS (k 4KB swizzled + v-frag 8KB), double-buffered.
// Per-tile: issue next-tile global loads early, compute SAD/exp/MFMA from LDS, ds_write late, barrier.
// k LDS layout: chunk c of row r stored at chunk (c ^ ((r>>3)&3)) -> the 4 lane-groups
// (which read rows r=g*8+e, broadcast within 16 lanes) hit disjoint banks.
__global__ __launch_bounds__(256) void attn_kernel(
    const unsigned* __restrict__ qq8, const unsigned* __restrict__ kq8,
    const uint4* __restrict__ vfrag, float* __restrict__ part)
{
    __shared__ unsigned kS[2][1024];   // [buf][row*16 + (chunk^sw)*4] dwords, 4 KB/buf
    __shared__ uint4    vS[2][512];    // [buf][entry*64 + lane], 8 KB/buf

    const int tid = threadIdx.x;
    const int wv_ = tid >> 6;          // wave 0..3 = q-row block
    const int l   = tid & 63;
    const int g   = l >> 4;            // 0..3
    const int m   = l & 15;
    const int qt  = blockIdx.x;        // 0..15
    const int h   = blockIdx.y, b = blockIdx.z;
    const int bh  = b * NHh + h;

    // q row (16 dwords = 64 u8); rows 1000..1023 are garbage but masked at write (exp2->finite)
    unsigned qv[16];
    {
        const uint4* qp = (const uint4*)(qq8 + ((size_t)bh * TPAD + qt * 64 + wv_ * 16 + m) * 16);
        *(uint4*)&qv[0]  = qp[0];
        *(uint4*)&qv[4]  = qp[1];
        *(uint4*)&qv[8]  = qp[2];
        *(uint4*)&qv[12] = qp[3];
    }

    const uint4* kg = (const uint4*)(kq8 + (size_t)bh * TPAD * 16);  // tile t at [t*256 + tid]
    const uint4* vg = vfrag + (size_t)bh * (16 * 512);               // tile t at [t*512 + ...]

    // staging indices for this thread (k): row tid>>2, chunk tid&3, swizzled dest
    const int krow = tid >> 2, kc = tid & 3;
    const int kdst = (krow << 2) + (kc ^ ((krow >> 3) & 3));   // uint4 index into kS[buf]

    // prologue: stage tile 0
    {
        uint4 k0 = kg[tid];
        uint4 v0 = vg[tid];
        uint4 v1 = vg[256 + tid];
        *(uint4*)&kS[0][kdst << 2] = k0;
        vS[0][tid] = v0;
        vS[0][256 + tid] = v1;
    }
    __syncthreads();

    f32x4 acc0 = {0.f,0.f,0.f,0.f}, acc1 = acc0, acc2 = acc0, acc3 = acc0;
    float dsum = 0.0f;

#pragma unroll 1
    for (int t = 0; t < 16; ++t) {
        const int cur = t & 1;

        // ---- issue next-tile loads early (latency hides under compute)
        const int tn = (t < 15) ? t + 1 : 15;
        uint4 kn  = kg[tn * 256 + tid];
        uint4 vn0 = vg[tn * 512 + tid];
        uint4 vn1 = vg[tn * 512 + 256 + tid];

        // ---- scores from LDS k tile
        bf16x8 A0, A1;
#pragma unroll
        for (int kk = 0; kk < 2; ++kk) {
            unsigned accu[8];
#pragma unroll
            for (int e = 0; e < 8; ++e) {
                const unsigned* kb = &kS[cur][(kk * 32 + (g << 3) + e) << 4];
                uint4 c0 = *(const uint4*)(kb + ((0 ^ g) << 2));
                uint4 c1 = *(const uint4*)(kb + ((1 ^ g) << 2));
                uint4 c2 = *(const uint4*)(kb + ((2 ^ g) << 2));
                uint4 c3 = *(const uint4*)(kb + ((3 ^ g) << 2));
                const unsigned* k0 = (const unsigned*)&c0;
                const unsigned* k1 = (const unsigned*)&c1;
                const unsigned* k2 = (const unsigned*)&c2;
                const unsigned* k3 = (const unsigned*)&c3;
                unsigned sa = 0u, sb = 0u;
#pragma unroll
                for (int w = 0; w < 4; ++w) sa = sad_u8(qv[w],      k0[w], sa);
#pragma unroll
                for (int w = 0; w < 4; ++w) sb = sad_u8(qv[4 + w],  k1[w], sb);
#pragma unroll
                for (int w = 0; w < 4; ++w) sa = sad_u8(qv[8 + w],  k2[w], sa);
#pragma unroll
                for (int w = 0; w < 4; ++w) sb = sad_u8(qv[12 + w], k3[w], sb);
                accu[e] = sa + sb;
            }
            const bool maskall = (t == 15) && (kk == 1) && (g >= 1);
            float p[8];
#pragma unroll
            for (int e = 0; e < 8; ++e) {
                p[e] = maskall ? 0.0f : __builtin_amdgcn_exp2f(CQ * (float)accu[e]);
                dsum += p[e];
            }
            bf16x8 A = mkbf(cvt_pk_bf16(p[0], p[1]), cvt_pk_bf16(p[2], p[3]),
                            cvt_pk_bf16(p[4], p[5]), cvt_pk_bf16(p[6], p[7]));
            if (kk == 0) A0 = A; else A1 = A;
        }

        // ---- PV via MFMA, V fragments from LDS (two halves of 4)
        {
            uint4 vf0 = vS[cur][0 * 64 + l], vf1 = vS[cur][1 * 64 + l];
            uint4 vf2 = vS[cur][2 * 64 + l], vf3 = vS[cur][3 * 64 + l];
            acc0 = __builtin_amdgcn_mfma_f32_16x16x32_bf16(A0, bfc(vf0), acc0, 0, 0, 0);
            acc1 = __builtin_amdgcn_mfma_f32_16x16x32_bf16(A0, bfc(vf1), acc1, 0, 0, 0);
            acc2 = __builtin_amdgcn_mfma_f32_16x16x32_bf16(A0, bfc(vf2), acc2, 0, 0, 0);
            acc3 = __builtin_amdgcn_mfma_f32_16x16x32_bf16(A0, bfc(vf3), acc3, 0, 0, 0);
        }
        {
            uint4 vf4 = vS[cur][4 * 64 + l], vf5 = vS[cur][5 * 64 + l];
            uint4 vf6 = vS[cur][6 * 64 + l], vf7 = vS[cur][7 * 64 + l];
            acc0 = __builtin_amdgcn_mfma_f32_16x16x32_bf16(A1, bfc(vf4), acc0, 0, 0, 0);
            acc1 = __builtin_amdgcn_mfma_f32_16x16x32_bf16(A1, bfc(vf5), acc1, 0, 0, 0);
            acc2 = __builtin_amdgcn_mfma_f32_16x16x32_bf16(A1, bfc(vf6), acc2, 0, 0, 0);
            acc3 = __builtin_amdgcn_mfma_f32_16x16x32_bf16(A1, bfc(vf7), acc3, 0, 0, 0);
        }

        // ---- write prefetched tile into the other buffer (safe: other buf not read this iter)
        if (t < 15) {
            *(uint4*)&kS[cur ^ 1][kdst << 2] = kn;
            vS[cur ^ 1][tid] = vn0;
            vS[cur ^ 1][256 + tid] = vn1;
        }
        __syncthreads();
    }

    // denominator: sum over the 4 lane-groups sharing m; +1 for the null row
    dsum += __shfl_xor(dsum, 16);
    dsum += __shfl_xor(dsum, 32);
    const float den = 1.0f + dsum;     // valid per lane for q-row index m

    // store: q-row = qt*64 + wv_*16 + g*4 + j, col = n*16 + m (accn)
#pragma unroll
    for (int j = 0; j < 4; ++j) {
        float dj = __shfl(den, g * 4 + j);
        int row = qt * 64 + wv_ * 16 + g * 4 + j;
        if (row < Tt) {
            float inv = 1.0f / dj;
            float* o = part + (((size_t)b * Tt + row) * NHh + h) * 64 + m;
            o[0]  = acc0[j] * inv;
            o[16] = acc1[j] * inv;
            o[32] = acc2[j] * inv;
            o[48] = acc3[j] * inv;
        }
    }
}

// ---------------- Kernel C: head-sum + ReLU + wf projection + residual ----------
__global__ __launch_bounds__(256) void finalize_kernel(
    const float* __restrict__ x, const float* __restrict__ wf,
    const float* __restrict__ part, float* __restrict__ out)
{
    __shared__ float wfs[64][65];
    __shared__ float osh[4][64];
    const int tid = threadIdx.x;
    for (int i = tid; i < 64 * 65; i += 256) wfs[i / 65][i % 65] = wf[i];
    const int wave = tid >> 6, lane = tid & 63;
    const int token = blockIdx.x * 4 + wave;   // 0..7999
    float o = 0.f;
    const float* pt = part + (size_t)token * NHh * Dd;
#pragma unroll
    for (int hh = 0; hh < NHh; ++hh) o += pt[hh * Dd + lane];
    o = fmaxf(o, 0.f);
    osh[wave][lane] = o;
    __syncthreads();
    float acc = wfs[lane][64];    // bias
#pragma unroll 8
    for (int w = 0; w < 64; ++w) acc += wfs[lane][w] * osh[wave][w];
    out[(size_t)token * Dd + lane] = x[(size_t)token * Dd + lane] + acc;
}

extern "C" void kernel_launch(void* const* d_in, const int* in_sizes, int n_in,
                              void* d_out, int out_size, void* d_ws, size_t ws_size,
                              hipStream_t stream)
{
    const float* x  = (const float*)d_in[0];
    const float* wq = (const float*)d_in[1];
    const float* wv = (const float*)d_in[2];
    const float* wk = (const float*)d_in[3];
    const float* wf = (const float*)d_in[4];
    float* out = (float*)d_out;

    char* base = (char*)d_ws;
    float*    part  = (float*)base;                                   // 16,384,000 B
    unsigned* qq8   = (unsigned*)(base + 16384000);                   //  4,194,304 B
    unsigned* kq8   = (unsigned*)(base + 16384000 + 4194304);         //  4,194,304 B
    uint4*    vfrag = (uint4*)(base + 16384000 + 2 * 4194304);        //  8,388,608 B

    prep_kernel<<<dim3(16, 16, Bb), 256, 0, stream>>>(x, wq, wv, wk, qq8, kq8, vfrag);
    attn_kernel<<<dim3(16, NHh, Bb), 256, 0, stream>>>(qq8, kq8, vfrag, part);
    finalize_kernel<<<2000, 256, 0, stream>>>(x, wf, part, out);
}